// Round 5
// baseline (681.401 us; speedup 1.0000x reference)
//
#include <hip/hip_runtime.h>
#include <stdint.h>

// OHEM MSE loss: exact k-th-largest via 2-round radix select on float bits
// (loss >= 0 so uint order == float order). norm = 2^23 -> *0x1p-23f exact.
//
// Round-3 kernel (resubmit x2; benches never ran due to GPU acquisition
// timeouts): hand-pipelined straight-line loads (depth-2/3, sched_barrier
// pinned) to force memory-level parallelism; hot loop has zero ballots and
// only the rare (hi==b, ~24k/16.7M) per-lane atomic; hist2 built from the
// compacted candidate list by a tiny kernel.

#define H2_BITS 17            // low bits resolved in round 2
#define H1_SIZE 32768         // 2^15 bins (top 15 bits)
#define H1_WORDS (H1_SIZE / 2)
#define H2_SIZE 131072        // 2^17 bins (low 17 bits)

// ws layout (bytes):
//   0       u32 hist1[2][32768]  (256 KB)
//   262144  u32 hist2[131072]    (512 KB)
//   786432  u32 meta[16]: [0]=b [1]=kprime [2]=thr [3]=overflow
//                         [4]=cnt_above [5]=cnt_cand [6]=cand_count
//   786496  double sums[2]: [0]=sum_above [1]=sum_cand
//   786560  uint2 cand[cap]
#define OFF_H2   262144
#define OFF_META 786432
#define OFF_SUMS 786496
#define OFF_CAND 786560

#define SB() __builtin_amdgcn_sched_barrier(0)

__device__ __forceinline__ void hist_add4(uint32_t* lh, float4 pv, float4 tv) {
    float d0 = pv.x - tv.x, d1 = pv.y - tv.y, d2 = pv.z - tv.z, d3 = pv.w - tv.w;
    uint32_t b0 = __float_as_uint(d0 * d0 * 0x1p-23f) >> H2_BITS;
    uint32_t b1 = __float_as_uint(d1 * d1 * 0x1p-23f) >> H2_BITS;
    uint32_t b2 = __float_as_uint(d2 * d2 * 0x1p-23f) >> H2_BITS;
    uint32_t b3 = __float_as_uint(d3 * d3 * 0x1p-23f) >> H2_BITS;
    atomicAdd(&lh[b0 >> 1], 1u << ((b0 & 1) * 16));
    atomicAdd(&lh[b1 >> 1], 1u << ((b1 & 1) * 16));
    atomicAdd(&lh[b2 >> 1], 1u << ((b2 & 1) * 16));
    atomicAdd(&lh[b3 >> 1], 1u << ((b3 & 1) * 16));
}

// Pass 1: LDS histogram of top-15 bits, packed 2xu16 (64 KB -> 2 blk/CU).
// Per-block elements = 8192 f4 * 4 = 32768 <= 65535, u16 safe.
__global__ __launch_bounds__(1024) void k_hist1(
    const float4* __restrict__ p, const float4* __restrict__ t,
    uint32_t* __restrict__ hist1, int n4)
{
    __shared__ uint32_t lh[H1_WORDS];
    for (int j = threadIdx.x; j < H1_WORDS; j += 1024) lh[j] = 0;
    __syncthreads();
    const int tid = threadIdx.x;
    const int base = blockIdx.x * 8192;
    if (base + 8192 <= n4) {
        const float4* pb = p + base;
        const float4* tb = t + base;
#define H1LD(u) float4 P##u = pb[tid + (u)*1024]; float4 T##u = tb[tid + (u)*1024];
#define H1PR(u) hist_add4(lh, P##u, T##u);
        H1LD(0) H1LD(1) H1LD(2)
        SB();
        H1LD(3) SB(); H1PR(0)
        H1LD(4) SB(); H1PR(1)
        H1LD(5) SB(); H1PR(2)
        H1LD(6) SB(); H1PR(3)
        H1LD(7) SB(); H1PR(4)
        H1PR(5) H1PR(6) H1PR(7)
#undef H1LD
#undef H1PR
    } else {
        for (int i = base + tid; i < n4; i += 1024) hist_add4(lh, p[i], t[i]);
    }
    __syncthreads();
    uint32_t* dst = hist1 + (blockIdx.x & 1) * H1_SIZE;
    const uint32_t rot = (blockIdx.x >> 1) * 64;
    for (int jj = threadIdx.x; jj < H1_WORDS; jj += 1024) {
        int j = (int)((jj + rot) & (H1_WORDS - 1));
        uint32_t v = lh[j];
        uint32_t c0 = v & 0xFFFFu, c1 = v >> 16;
        if (c0) atomicAdd(&dst[2 * j], c0);
        if (c1) atomicAdd(&dst[2 * j + 1], c1);
    }
}

// Find bin b containing the k-th largest (suffix scan from top). 1 block.
__global__ __launch_bounds__(1024) void k_scan1(
    const uint32_t* __restrict__ hist1, const int* __restrict__ min_kept,
    uint32_t* __restrict__ meta)
{
    __shared__ uint32_t psum[1024];
    __shared__ uint32_t gsuf[64];
    const int t = threadIdx.x;
    const uint32_t k = (uint32_t)(*min_kept);
    const uint32_t* h0 = hist1;
    const uint32_t* h1 = hist1 + H1_SIZE;
    const int per = H1_SIZE / 1024;                 // 32 bins/thread
    const int base = t * per;
    uint32_t s = 0;
    #pragma unroll
    for (int i = 0; i < per; i++) s += h0[base + i] + h1[base + i];
    psum[t] = s;
    __syncthreads();
    if (t < 64) {
        uint32_t g = 0;
        for (int i = 0; i < 16; i++) g += psum[t * 16 + i];
        uint32_t v = g;
        #pragma unroll
        for (int off = 1; off < 64; off <<= 1) {
            uint32_t o = __shfl_down(v, off);
            if (t + off < 64) v += o;
        }
        gsuf[t] = v;                                 // sum of groups t..63
    }
    __syncthreads();
    const int g = t >> 4;
    uint32_t cum = (g < 63) ? gsuf[g + 1] : 0;
    const int gend = g * 16 + 15;
    for (int j = t + 1; j <= gend; j++) cum += psum[j];
    if (cum < k && k <= cum + psum[t]) {
        uint32_t c = cum;
        for (int i = per - 1; i >= 0; i--) {
            uint32_t h = h0[base + i] + h1[base + i];
            c += h;
            if (c >= k) {
                meta[0] = (uint32_t)(base + i);      // coarse bin b
                meta[1] = k - (c - h);               // rank within bin (1-idx)
                break;
            }
        }
    }
}

// Main pass: branchless sum/count for hi>b; rare per-lane compact for hi==b.
__global__ __launch_bounds__(256) void k_main(
    const float4* __restrict__ p, const float4* __restrict__ t,
    const float4* __restrict__ w, uint32_t* meta,
    double* __restrict__ sums, uint2* __restrict__ cand,
    uint32_t cap, int n4)
{
    const uint32_t b = meta[0];
    double lsum = 0.0;
    uint32_t lcnt = 0;
    const int tid = threadIdx.x;
    const int base = blockIdx.x * 4096;

    auto proc = [&](float4 pv, float4 tv, float4 wv) {
        float d0 = pv.x - tv.x, d1 = pv.y - tv.y, d2 = pv.z - tv.z, d3 = pv.w - tv.w;
        float l0 = d0 * d0 * 0x1p-23f, l1 = d1 * d1 * 0x1p-23f;
        float l2 = d2 * d2 * 0x1p-23f, l3 = d3 * d3 * 0x1p-23f;
        float wa[4] = {wv.x, wv.y, wv.z, wv.w};
        float lo[4] = {l0, l1, l2, l3};
        #pragma unroll
        for (int c = 0; c < 4; c++) {
            uint32_t bits = __float_as_uint(lo[c]);
            uint32_t hi = bits >> H2_BITS;
            bool above = hi > b;
            lcnt += above ? 1u : 0u;
            lsum += above ? (double)(wa[c] * lo[c]) : 0.0;
            if (hi == b) {                           // ~0.14% of elements
                uint32_t idx = atomicAdd(&meta[6], 1u);
                if (idx < cap) cand[idx] = make_uint2(bits, __float_as_uint(wa[c]));
                else meta[3] = 1u;                   // overflow -> fallback
            }
        }
    };

    if (base + 4096 <= n4) {
        const float4* pb = p + base;
        const float4* tb = t + base;
        const float4* wb = w + base;
#define MLD(u) float4 P##u = pb[tid + (u)*256]; float4 T##u = tb[tid + (u)*256]; \
               float4 W##u = wb[tid + (u)*256];
#define MPR(u) proc(P##u, T##u, W##u);
        MLD(0) MLD(1)
        SB();
        MLD(2)  SB(); MPR(0)
        MLD(3)  SB(); MPR(1)
        MLD(4)  SB(); MPR(2)
        MLD(5)  SB(); MPR(3)
        MLD(6)  SB(); MPR(4)
        MLD(7)  SB(); MPR(5)
        MLD(8)  SB(); MPR(6)
        MLD(9)  SB(); MPR(7)
        MLD(10) SB(); MPR(8)
        MLD(11) SB(); MPR(9)
        MLD(12) SB(); MPR(10)
        MLD(13) SB(); MPR(11)
        MLD(14) SB(); MPR(12)
        MLD(15) SB(); MPR(13)
        MPR(14) MPR(15)
#undef MLD
#undef MPR
    } else {
        for (int i = base + tid; i < n4; i += 256) proc(p[i], t[i], w[i]);
    }

    #pragma unroll
    for (int off = 32; off; off >>= 1) {
        lsum += __shfl_down(lsum, off);
        lcnt += __shfl_down(lcnt, off);
    }
    __shared__ double sred[4];
    __shared__ uint32_t cred[4];
    const int wid = threadIdx.x >> 6, lane = threadIdx.x & 63;
    if (lane == 0) { sred[wid] = lsum; cred[wid] = lcnt; }
    __syncthreads();
    if (threadIdx.x == 0) {
        double bs = sred[0] + sred[1] + sred[2] + sred[3];
        uint32_t bc = cred[0] + cred[1] + cred[2] + cred[3];
        atomicAdd(&sums[0], bs);
        atomicAdd(&meta[4], bc);
    }
}

// Build hist2 (low-17 bits) from compacted candidates; full-pass fallback on
// overflow (never with this data).
__global__ __launch_bounds__(256) void k_hist2b(
    const float4* __restrict__ p, const float4* __restrict__ t,
    uint32_t* __restrict__ meta, const uint2* __restrict__ cand,
    uint32_t cap, uint32_t* __restrict__ hist2, int n4)
{
    if (!meta[3]) {
        uint32_t cnt = meta[6];
        if (cnt > cap) cnt = cap;
        for (uint32_t i = blockIdx.x * 256 + threadIdx.x; i < cnt;
             i += gridDim.x * 256) {
            atomicAdd(&hist2[cand[i].x & (H2_SIZE - 1)], 1u);
        }
    } else {
        const uint32_t b = meta[0];
        const int S = gridDim.x * 256;
        for (int i = blockIdx.x * 256 + threadIdx.x; i < n4; i += S) {
            float4 pv = p[i], tv = t[i];
            float d[4] = {pv.x - tv.x, pv.y - tv.y, pv.z - tv.z, pv.w - tv.w};
            #pragma unroll
            for (int c = 0; c < 4; c++) {
                uint32_t bits = __float_as_uint(d[c] * d[c] * 0x1p-23f);
                if ((bits >> H2_BITS) == b)
                    atomicAdd(&hist2[bits & (H2_SIZE - 1)], 1u);
            }
        }
    }
}

// Resolve exact threshold bits within bin b.
__global__ __launch_bounds__(1024) void k_scan2(
    const uint32_t* __restrict__ hist2, uint32_t* meta)
{
    __shared__ uint32_t psum[1024];
    __shared__ uint32_t gsuf[64];
    const int t = threadIdx.x;
    const uint32_t k = meta[1];
    const uint32_t b = meta[0];
    const int per = H2_SIZE / 1024;                  // 128 bins/thread
    const int base = t * per;
    uint32_t s = 0;
    for (int i = 0; i < per; i++) s += hist2[base + i];
    psum[t] = s;
    __syncthreads();
    if (t < 64) {
        uint32_t g = 0;
        for (int i = 0; i < 16; i++) g += psum[t * 16 + i];
        uint32_t v = g;
        #pragma unroll
        for (int off = 1; off < 64; off <<= 1) {
            uint32_t o = __shfl_down(v, off);
            if (t + off < 64) v += o;
        }
        gsuf[t] = v;
    }
    __syncthreads();
    const int g = t >> 4;
    uint32_t cum = (g < 63) ? gsuf[g + 1] : 0;
    const int gend = g * 16 + 15;
    for (int j = t + 1; j <= gend; j++) cum += psum[j];
    if (cum < k && k <= cum + psum[t]) {
        uint32_t c = cum;
        for (int i = per - 1; i >= 0; i--) {
            uint32_t h = hist2[base + i];
            c += h;
            if (c >= k) {
                meta[2] = (b << H2_BITS) | (uint32_t)(base + i);
                break;
            }
        }
    }
}

// Accumulate candidates strictly above threshold; full-pass fallback only on
// overflow.
__global__ __launch_bounds__(256) void k_cand(
    const float4* __restrict__ p, const float4* __restrict__ t,
    const float4* __restrict__ w, uint32_t* meta,
    const uint2* __restrict__ cand, uint32_t cap,
    double* __restrict__ sums, int n4)
{
    const uint32_t thr = meta[2];
    const uint32_t overflow = meta[3];
    double lsum = 0.0;
    uint32_t lcnt = 0;
    if (!overflow) {
        uint32_t cnt = meta[6];
        if (cnt > cap) cnt = cap;
        for (uint32_t i = blockIdx.x * 256 + threadIdx.x; i < cnt;
             i += gridDim.x * 256) {
            uint2 e = cand[i];
            if (e.x > thr) {
                lcnt++;
                lsum += (double)(__uint_as_float(e.y) * __uint_as_float(e.x));
            }
        }
    } else {
        const uint32_t bb = meta[0];
        const int S = gridDim.x * 256;
        for (int i = blockIdx.x * 256 + threadIdx.x; i < n4; i += S) {
            float4 pv = p[i], tv = t[i], wv = w[i];
            float d[4] = {pv.x - tv.x, pv.y - tv.y, pv.z - tv.z, pv.w - tv.w};
            float wa[4] = {wv.x, wv.y, wv.z, wv.w};
            #pragma unroll
            for (int c = 0; c < 4; c++) {
                float loss = d[c] * d[c] * 0x1p-23f;
                uint32_t bits = __float_as_uint(loss);
                if ((bits >> H2_BITS) == bb && bits > thr) {
                    lcnt++;
                    lsum += (double)(wa[c] * loss);
                }
            }
        }
    }
    #pragma unroll
    for (int off = 32; off; off >>= 1) {
        lsum += __shfl_down(lsum, off);
        lcnt += __shfl_down(lcnt, off);
    }
    __shared__ double sred[4];
    __shared__ uint32_t cred[4];
    const int wid = threadIdx.x >> 6, lane = threadIdx.x & 63;
    if (lane == 0) { sred[wid] = lsum; cred[wid] = lcnt; }
    __syncthreads();
    if (threadIdx.x == 0) {
        double bs = sred[0] + sred[1] + sred[2] + sred[3];
        uint32_t bc = cred[0] + cred[1] + cred[2] + cred[3];
        atomicAdd(&sums[1], bs);
        atomicAdd(&meta[5], bc);
    }
}

__global__ __launch_bounds__(64) void k_final(
    const double* __restrict__ sums, const uint32_t* __restrict__ meta,
    float* __restrict__ out)
{
    if (threadIdx.x == 0 && blockIdx.x == 0) {
        double s = sums[0] + sums[1];
        double c = (double)(meta[4] + meta[5]);
        out[0] = (float)(s / c);
    }
}

extern "C" void kernel_launch(void* const* d_in, const int* in_sizes, int n_in,
                              void* d_out, int out_size, void* d_ws, size_t ws_size,
                              hipStream_t stream) {
    const float* p = (const float*)d_in[0];
    const float* t = (const float*)d_in[1];
    const float* w = (const float*)d_in[2];
    const int* mk = (const int*)d_in[3];
    float* out = (float*)d_out;
    const int n = in_sizes[0];       // 16777216, divisible by 4
    const int n4 = n / 4;

    uint8_t* ws = (uint8_t*)d_ws;
    uint32_t* hist1 = (uint32_t*)ws;
    uint32_t* hist2 = (uint32_t*)(ws + OFF_H2);
    uint32_t* meta  = (uint32_t*)(ws + OFF_META);
    double*   sums  = (double*)(ws + OFF_SUMS);
    uint2*    cand  = (uint2*)(ws + OFF_CAND);
    uint32_t cap = 0;
    if (ws_size > OFF_CAND + 8) {
        cap = (uint32_t)((ws_size - OFF_CAND) / 8);
    }

    hipMemsetAsync(d_ws, 0, OFF_CAND, stream);
    const int nb1 = (n4 + 8191) / 8192;
    const int nbm = (n4 + 4095) / 4096;
    k_hist1<<<nb1, 1024, 0, stream>>>((const float4*)p, (const float4*)t, hist1, n4);
    k_scan1<<<1, 1024, 0, stream>>>(hist1, mk, meta);
    k_main<<<nbm, 256, 0, stream>>>((const float4*)p, (const float4*)t,
                                    (const float4*)w, meta, sums, cand, cap, n4);
    k_hist2b<<<32, 256, 0, stream>>>((const float4*)p, (const float4*)t,
                                     meta, cand, cap, hist2, n4);
    k_scan2<<<1, 1024, 0, stream>>>(hist2, meta);
    k_cand<<<64, 256, 0, stream>>>((const float4*)p, (const float4*)t,
                                   (const float4*)w, meta, cand, cap, sums, n4);
    k_final<<<1, 64, 0, stream>>>(sums, meta, out);
}